// Round 6
// baseline (1576610.156 us; speedup 1.0000x reference)
//
#include <hip/hip_runtime.h>
#include <stdint.h>

typedef _Float16 f16;
typedef f16 f16x2 __attribute__((ext_vector_type(2)));

#define T_LEN 32768
#define HID   512
#define IN_D  1024
#define OUT_D 128
#define NT    1024         // scan threads: 16 waves, 4/SIMD -> RA's native 128-VGPR point
// Per-thread W: 4 rows x 64 k = 128 dwords (f16x2), as 32 uint4 "j" (j=c8*4+rl):
//   j in [0,20)  -> VGPR wreg[80]
//   j in [20,29) -> LDS wlds4[(j-20)*NT+t]   (147456 B, lane-contiguous)
//   j in [29,32) -> L2 stream (48 KB/matvec, issued at mv entry)

__device__ __forceinline__ float dot2f(uint32_t w, uint32_t v, float acc) {
    return __builtin_amdgcn_fdot2(__builtin_bit_cast(f16x2, w),
                                  __builtin_bit_cast(f16x2, v), acc, false);
}
__device__ __forceinline__ float fast_tanh(float z) {
    float e = __expf(2.f * z);
    return 1.f - 2.f * __builtin_amdgcn_rcpf(e + 1.f);
}

// ---------------------------------------------------------------------------
// K0: pack W (fp32) -> f16x2, layout dst4[j*NT + t]; element (j,mm):
// rl=j&3, c8=j>>2, row=4*(t>>3)+rl, k0=(t&7)*64 + c8*8 + mm*2.
// Same layout for W_ode and W_h (identical consumption index algebra).
// ---------------------------------------------------------------------------
__global__ __launch_bounds__(NT) void k_prep(const float* __restrict__ W_ode,
                                             const float* __restrict__ W_h,
                                             uint32_t* __restrict__ ode_prep,
                                             uint32_t* __restrict__ wh_prep) {
    const int t = threadIdx.x;
    const float* W = blockIdx.x ? W_h : W_ode;
    uint4* dst = (uint4*)(blockIdx.x ? wh_prep : ode_prep);
    const int rg = t >> 3, kg = t & 7;
    for (int j = 0; j < 32; ++j) {
        const int rl = j & 3, c8 = j >> 2;
        const int row = rg * 4 + rl;
        uint32_t c[4];
#pragma unroll
        for (int mm = 0; mm < 4; ++mm) {
            const int k0 = kg * 64 + c8 * 8 + mm * 2;
            f16x2 pk;
            pk[0] = (f16)W[row * HID + k0];
            pk[1] = (f16)W[row * HID + k0 + 1];
            c[mm] = __builtin_bit_cast(uint32_t, pk);
        }
        dst[j * NT + t] = uint4{c[0], c[1], c[2], c[3]};
    }
}

// ---------------------------------------------------------------------------
// K1: pre[i][j] = W_in @ x_i + b_in + b_h   (fp32 tiled GEMM) — unchanged.
// ---------------------------------------------------------------------------
__global__ __launch_bounds__(512) void k_pre(const float* __restrict__ x,
                                             const float* __restrict__ W_in,
                                             const float* __restrict__ b_in,
                                             const float* __restrict__ b_h,
                                             float* __restrict__ pre32,
                                             uint16_t* __restrict__ pre16,
                                             int preF32) {
    __shared__ float xs[64][34];
    __shared__ float wsh[256][34];
    const int t  = threadIdx.x;
    const int i0 = (blockIdx.x >> 1) * 64;
    const int j0 = (blockIdx.x & 1) * 256;
    const int ti = t >> 5, tj = t & 31;

    float acc[4][8];
#pragma unroll
    for (int a = 0; a < 4; ++a)
#pragma unroll
        for (int b = 0; b < 8; ++b) acc[a][b] = 0.f;

    for (int kb = 0; kb < 32; ++kb) {
        __syncthreads();
        {   // x tile: 64 x 32
            int r = t >> 3, c = (t & 7) * 4;
            float4 v = *(const float4*)&x[(size_t)(i0 + r) * IN_D + kb * 32 + c];
            xs[r][c] = v.x; xs[r][c + 1] = v.y; xs[r][c + 2] = v.z; xs[r][c + 3] = v.w;
        }
        {   // W tile: 256 x 32
            int jr = t >> 1, c0 = (t & 1) * 16;
#pragma unroll
            for (int qd = 0; qd < 4; ++qd) {
                float4 v = *(const float4*)&W_in[(size_t)(j0 + jr) * IN_D + kb * 32 + c0 + qd * 4];
                wsh[jr][c0 + qd * 4]     = v.x; wsh[jr][c0 + qd * 4 + 1] = v.y;
                wsh[jr][c0 + qd * 4 + 2] = v.z; wsh[jr][c0 + qd * 4 + 3] = v.w;
            }
        }
        __syncthreads();
#pragma unroll 4
        for (int k = 0; k < 32; ++k) {
            float xv[4], wv[8];
#pragma unroll
            for (int ii = 0; ii < 4; ++ii) xv[ii] = xs[ti * 4 + ii][k];
#pragma unroll
            for (int jj = 0; jj < 8; ++jj) wv[jj] = wsh[tj + 32 * jj][k];
#pragma unroll
            for (int ii = 0; ii < 4; ++ii)
#pragma unroll
                for (int jj = 0; jj < 8; ++jj)
                    acc[ii][jj] = fmaf(xv[ii], wv[jj], acc[ii][jj]);
        }
    }
#pragma unroll
    for (int ii = 0; ii < 4; ++ii)
#pragma unroll
        for (int jj = 0; jj < 8; ++jj) {
            int ig = i0 + ti * 4 + ii, jg = j0 + tj + 32 * jj;
            float r = acc[ii][jj] + b_in[jg] + b_h[jg];
            if (preF32) pre32[(size_t)ig * HID + jg] = r;
            else        pre16[(size_t)ig * HID + jg] = __builtin_bit_cast(uint16_t, (f16)r);
        }
}

// ---------------------------------------------------------------------------
// K2: sequential scan. 1024 threads (16 waves, 4/SIMD = the allocator's
// native 128-VGPR occupancy). Thread t: rows 4*(t>>3)..+3 over k slice
// [(t&7)*64, +64). After reduce, lane owns row 4*(t>>3)+(t&3... (kg&3)).
// v-buffer keeps the 144B kg-stride (9x16B) -> conflict-free b128 broadcast.
// ---------------------------------------------------------------------------
__global__ __launch_bounds__(NT) void k_scan(
    const uint32_t* __restrict__ ode_prep, const uint32_t* __restrict__ wh_prep,
    const float* __restrict__ pre32, const uint16_t* __restrict__ pre16, int preF32,
    const float* __restrict__ tarr, const float* __restrict__ b_ode,
    const float* __restrict__ W_dec, const float* __restrict__ b_dec,
    float* __restrict__ out)
{
    __shared__ uint4 wlds4[9 * NT];                   // 147456 B, lane-contiguous
    __shared__ __align__(16) uint16_t vbuf[2][576];   // f16 v, 64-elem groups + 8 pad
    __shared__ float hbuf[HID];

    const int t   = threadIdx.x;
    const int kg  = t & 7;
    const int rg  = t >> 3;
    const int row = rg * 4 + (kg & 3);     // row this lane owns post-reduce
    const uint4* ode4 = (const uint4*)ode_prep;
    const uint4* wh4  = (const uint4*)wh_prep;

    uint32_t wreg[80];
#pragma unroll
    for (int j = 0; j < 20; ++j) {
        uint4 w = ode4[j * NT + t];
        wreg[4 * j] = w.x; wreg[4 * j + 1] = w.y;
        wreg[4 * j + 2] = w.z; wreg[4 * j + 3] = w.w;
    }
#pragma unroll
    for (int c = 0; c < 9; ++c)
        wlds4[c * NT + t] = ode4[(20 + c) * NT + t];

    const float bo = b_ode[row];
    __syncthreads();

    int cur = 1;
    auto push1 = [&](float val) {          // owner lanes publish v[row]
        int nxt = cur ^ 1;
        if (kg < 4)
            vbuf[nxt][(row >> 6) * 72 + (row & 63)] =
                __builtin_bit_cast(uint16_t, (f16)val);
        __syncthreads();
        cur = nxt;
    };

    // k-reduce over the 8 kg lanes; payload-halving (masks 1,2) + allreduce(4).
    // Lane ends with full sum of row rg*4 + (kg&3) (duplicated across kg^4).
    auto reduce4 = [&](float acc[4]) -> float {
        const bool o1 = kg & 1, o2 = (kg >> 1) & 1;
        float b[2];
#pragma unroll
        for (int j2 = 0; j2 < 2; ++j2) {
            float got = __shfl_xor(o1 ? acc[2 * j2] : acc[2 * j2 + 1], 1);
            b[j2] = (o1 ? acc[2 * j2 + 1] : acc[2 * j2]) + got;
        }
        float got2 = __shfl_xor(o2 ? b[0] : b[1], 2);
        float c = (o2 ? b[1] : b[0]) + got2;
        c += __shfl_xor(c, 4);
        return c;
    };

    // z = (W_ode v)[row]
    auto mv_ode = [&]() -> float {
        float acc[4] = {0.f, 0.f, 0.f, 0.f};
        uint4 st0 = ode4[29 * NT + t];     // L2 stream, used at c8=7
        uint4 st1 = ode4[30 * NT + t];
        uint4 st2 = ode4[31 * NT + t];
        const char* vb = (const char*)&vbuf[cur][0] + kg * 144;
#pragma unroll
        for (int c8 = 0; c8 < 8; ++c8) {
            const uint4 vv = *(const uint4*)(vb + c8 * 16);
#pragma unroll
            for (int rl = 0; rl < 4; ++rl) {
                if (c8 < 5) {
                    const int jb = (c8 * 4 + rl) * 4;
                    acc[rl] = dot2f(wreg[jb],     vv.x, acc[rl]);
                    acc[rl] = dot2f(wreg[jb + 1], vv.y, acc[rl]);
                    acc[rl] = dot2f(wreg[jb + 2], vv.z, acc[rl]);
                    acc[rl] = dot2f(wreg[jb + 3], vv.w, acc[rl]);
                } else {
                    uint4 wq;
                    if (c8 == 5)      wq = wlds4[rl * NT + t];          // j=20+rl
                    else if (c8 == 6) wq = wlds4[(4 + rl) * NT + t];    // j=24+rl
                    else wq = (rl == 0) ? wlds4[8 * NT + t]             // j=28
                            : (rl == 1) ? st0 : (rl == 2) ? st1 : st2;  // j=29..31
                    acc[rl] = dot2f(wq.x, vv.x, acc[rl]);
                    acc[rl] = dot2f(wq.y, vv.y, acc[rl]);
                    acc[rl] = dot2f(wq.z, vv.z, acc[rl]);
                    acc[rl] = dot2f(wq.w, vv.w, acc[rl]);
                }
            }
        }
        return reduce4(acc);
    };

    // z = (W_h v)[row]; W_h streamed from L2 (512 KB), 4-uint4 rolling ring
    auto mv_wh = [&]() -> float {
        float acc[4] = {0.f, 0.f, 0.f, 0.f};
        const char* vb = (const char*)&vbuf[cur][0] + kg * 144;
        uint4 ring[4];
#pragma unroll
        for (int r = 0; r < 4; ++r) ring[r] = wh4[r * NT + t];
        uint4 vvq;
#pragma unroll
        for (int j = 0; j < 32; ++j) {
            const int c8 = j >> 2, rl = j & 3;
            if (rl == 0) vvq = *(const uint4*)(vb + c8 * 16);
            const uint4 w = ring[j & 3];
            if (j + 4 < 32) ring[j & 3] = wh4[(j + 4) * NT + t];
            acc[rl] = dot2f(w.x, vvq.x, acc[rl]);
            acc[rl] = dot2f(w.y, vvq.y, acc[rl]);
            acc[rl] = dot2f(w.z, vvq.z, acc[rl]);
            acc[rl] = dot2f(w.w, vvq.w, acc[rl]);
        }
        return reduce4(acc);
    };

    // h0 = tanh(pre[0][row])
    float h;
    {
        float p0 = preF32 ? pre32[row] : (float)__builtin_bit_cast(f16, pre16[row]);
        h = fast_tanh(p0);
    }
    push1(h);
    float tprev = tarr[0];

#pragma unroll 1
    for (int i = 1; i < T_LEN; ++i) {
        float tc  = tarr[i];
        float dtt = tc - tprev; tprev = tc;
        float dt  = 0.25f * dtt;            // N_SUB = 4
        float hdt = 0.5f * dt;
        float sixth = dt * (1.f / 6.f);
        float pv = preF32 ? pre32[(size_t)i * HID + row]
                          : (float)__builtin_bit_cast(f16, pre16[(size_t)i * HID + row]);
#pragma unroll 1
        for (int sub = 0; sub < 4; ++sub) {
            float ks = 0.f;
#pragma unroll 1
            for (int s = 0; s < 4; ++s) {
                float z = mv_ode();
                float k = fast_tanh(z + bo);
                float wk = (s == 1 || s == 2) ? 2.f : 1.f;
                ks = fmaf(wk, k, ks);
                float n;
                if (s == 3) { h = fmaf(sixth, ks, h); n = h; }
                else        { float a = (s == 2) ? dt : hdt; n = fmaf(a, k, h); }
                push1(n);
            }
        }
        float zh = mv_wh();
        h = fast_tanh(pv + zh);
        push1(h);
    }

    // decode: out = W_dec @ h + b_dec
    if (kg < 4) hbuf[row] = h;
    __syncthreads();
    if (t < OUT_D) {
        float a = b_dec[t];
#pragma unroll 4
        for (int r4 = 0; r4 < 128; ++r4) {
            float4 w = *(const float4*)&W_dec[t * HID + r4 * 4];
            a = fmaf(w.x, hbuf[r4 * 4],     a);
            a = fmaf(w.y, hbuf[r4 * 4 + 1], a);
            a = fmaf(w.z, hbuf[r4 * 4 + 2], a);
            a = fmaf(w.w, hbuf[r4 * 4 + 3], a);
        }
        out[t] = a;
    }
}

// ---------------------------------------------------------------------------
extern "C" void kernel_launch(void* const* d_in, const int* in_sizes, int n_in,
                              void* d_out, int out_size, void* d_ws, size_t ws_size,
                              hipStream_t stream) {
    const float* tarr  = (const float*)d_in[0];
    const float* x     = (const float*)d_in[1];
    const float* W_in  = (const float*)d_in[2];
    const float* b_in  = (const float*)d_in[3];
    const float* W_h   = (const float*)d_in[4];
    const float* b_h   = (const float*)d_in[5];
    const float* W_ode = (const float*)d_in[6];
    const float* b_ode = (const float*)d_in[7];
    const float* W_dec = (const float*)d_in[8];
    const float* b_dec = (const float*)d_in[9];
    float* out = (float*)d_out;

    uint8_t*  ws       = (uint8_t*)d_ws;
    uint32_t* ode_prep = (uint32_t*)(ws);                  // 512 KB
    uint32_t* wh_prep  = (uint32_t*)(ws + (512u << 10));   // 512 KB
    void*     pre      = (void*)(ws + (1u << 20));         // 64 MB f32 or 32 MB f16

    size_t need32 = (1u << 20) + (size_t)T_LEN * HID * 4 + 4096;
    int preF32 = (ws_size >= need32) ? 1 : 0;

    hipLaunchKernelGGL(k_prep, dim3(2), dim3(NT), 0, stream, W_ode, W_h, ode_prep, wh_prep);
    hipLaunchKernelGGL(k_pre,  dim3(1024), dim3(512), 0, stream, x, W_in, b_in, b_h,
                       (float*)pre, (uint16_t*)pre, preF32);
    hipLaunchKernelGGL(k_scan, dim3(1), dim3(NT), 0, stream, ode_prep, wh_prep,
                       (const float*)pre, (const uint16_t*)pre, preF32,
                       tarr, b_ode, W_dec, b_dec, out);
}